// Round 4
// baseline (379.452 us; speedup 1.0000x reference)
//
#include <hip/hip_runtime.h>
#include <math.h>

#define SB 8
#define SS 2048
#define SH 768
#define ALPHA 0.5f
#define WV 8           // waves per block
#define TI 16          // q-rows per block (2 per wave: i and i+8)
#define JC 16          // k-rows staged per chunk
#define RS4 193        // LDS row stride in float4 (772 floats = 3088 B)
#define NCHUNK 5       // covers [i0-31, i0+48] >= needed [i0-31, i0+47]

// ws float layout:
// 0                    : kw   [SB*SS]  = km * (1/||k||)
// 16384                : qw   [SB*SS]  = qm * (1/||q||)
// 32768                : ksum [SB*SH]
// 38912                : Nk[8], qsum[8], acc[8]

__device__ __forceinline__ float dot4(float4 a, float4 b) {
  return a.x*b.x + a.y*b.y + a.z*b.z + a.w*b.w;
}

__device__ __forceinline__ void g2lds16(const float* g, float* l) {
  __builtin_amdgcn_global_load_lds(
      (const __attribute__((address_space(1))) void*)g,
      (__attribute__((address_space(3))) void*)l, 16, 0, 0);
}

// rows 0..SB*SS-1 : K -> kw ; rows SB*SS.. : Q -> qw.
// Fused: block-level mask partial sums -> Nk / qsum atomics.
__global__ __launch_bounds__(256) void norm_kernel(
    const float* __restrict__ Q, const float* __restrict__ K,
    const float* __restrict__ qm, const float* __restrict__ km,
    float* __restrict__ qw, float* __restrict__ kw,
    float* __restrict__ Nk, float* __restrict__ qsum) {
  __shared__ float sm[4];
  int lane = threadIdx.x & 63;
  int w = threadIdx.x >> 6;
  int r2 = blockIdx.x * 4 + w;
  bool isQ = r2 >= SB * SS;
  int r = isQ ? r2 - SB * SS : r2;
  const float4* rv = (const float4*)((isQ ? Q : K) + (size_t)r * SH);
  float4 a = rv[lane], b4 = rv[lane + 64], c = rv[lane + 128];
  float s = dot4(a, a) + dot4(b4, b4) + dot4(c, c);
  #pragma unroll
  for (int m = 1; m < 64; m <<= 1) s += __shfl_xor(s, m, 64);
  float mask = (isQ ? qm : km)[r];
  if (lane == 0) {
    (isQ ? qw : kw)[r] = mask / fmaxf(sqrtf(s), 1e-12f);
    sm[w] = mask;
  }
  __syncthreads();
  if (threadIdx.x == 0) {
    int b = r >> 11;
    atomicAdd((isQ ? qsum : Nk) + b, sm[0] + sm[1] + sm[2] + sm[3]);
  }
}

__global__ __launch_bounds__(256) void ksum_kernel(const float* __restrict__ K,
                                                   const float* __restrict__ kw,
                                                   float* __restrict__ ksum) {
  int b = blockIdx.y, jc = blockIdx.x, t = threadIdx.x;
  __shared__ float wsh[64];
  int j0 = jc * 64;
  if (t < 64) wsh[t] = kw[b * SS + j0 + t];
  __syncthreads();
  float a0 = 0.f, a1 = 0.f, a2 = 0.f;
  const float* base = K + ((size_t)b * SS + j0) * SH;
  for (int jj = 0; jj < 64; jj++) {
    float wv = wsh[jj];
    if (wv != 0.0f) {
      const float* rp = base + (size_t)jj * SH;
      a0 += rp[t] * wv;
      a1 += rp[t + 256] * wv;
      a2 += rp[t + 512] * wv;
    }
  }
  atomicAdd(&ksum[b * SH + t], a0);
  atomicAdd(&ksum[b * SH + t + 256], a1);
  atomicAdd(&ksum[b * SH + t + 512], a2);
}

// One wave owns TWO q-rows (i and i+8); each staged k-row read feeds 2 dots.
__global__ __launch_bounds__(512, 4) void band_kernel(
    const float* __restrict__ Q, const float* __restrict__ K,
    const float* __restrict__ temp,
    const float* __restrict__ qw, const float* __restrict__ kw,
    const float* __restrict__ ksum, const float* __restrict__ Nk,
    float* __restrict__ acc) {
  __shared__ float4 kb[JC * RS4];     // 49408 B
  __shared__ float tab_s[64];
  __shared__ float kwc[JC];
  __shared__ float wsum[WV];
  int tid = threadIdx.x;
  int w = tid >> 6, lane = tid & 63, g = lane >> 4, u = lane & 15;
  int blk = blockIdx.x;
  int b = blk >> 7;                    // grid = 8 * 128
  int i0 = (blk & 127) * TI;
  int i = i0 + w;                      // first q-row (i2 = i + 8)
  int r = b * SS + i;
  if (tid < 64) {
    float invt = 1.0f / temp[0];
    tab_s[tid] = __expf(-ALPHA * fabsf((float)(tid - 31))) * invt;
  }
  // load both q fragments once, fold in qw (qm/||q||)
  float qa = qw[r], qb = qw[r + 8];
  const float4* qra = (const float4*)(Q + (size_t)r * SH);
  const float4* qrb = (const float4*)(Q + (size_t)(r + 8) * SH);
  float4 qfa[12], qfb[12];
  #pragma unroll
  for (int m = 0; m < 12; ++m) {
    float4 va = qra[u + 16 * m];
    va.x *= qa; va.y *= qa; va.z *= qa; va.w *= qa;
    qfa[m] = va;
    float4 vb = qrb[u + 16 * m];
    vb.x *= qb; vb.y *= qb; vb.z *= qb; vb.w *= qb;
    qfb[m] = vb;
  }
  // far-field rank-1 terms (partial; reduced at the end)
  const float4* ks = (const float4*)(ksum + (size_t)b * SH);
  float d0a = 0.f, d0b = 0.f;
  #pragma unroll
  for (int mm = 0; mm < 3; ++mm) {
    int m = 3 * g + mm;
    float4 kv = ks[u + 16 * m];
    d0a += dot4(qfa[m], kv);
    d0b += dot4(qfb[m], kv);
  }

  float ana = 0.f, ada = 0.f, anb = 0.f, adb = 0.f;
  const float* Kb = K + (size_t)b * SS * SH;
  const float* kwb = kw + b * SS;
  float* ldsf = (float*)kb;

  for (int c = 0; c < NCHUNK; ++c) {
    int jlo = i0 - 31 + JC * c;
    __syncthreads();                   // LDS reuse guard
    #pragma unroll
    for (int q = 0; q < 6; ++q) {      // 8 waves x 6 = 48 issues = 16 rows x 3 parts
      int rrow = 2 * w + (q >= 3 ? 1 : 0);
      int part = q - (q >= 3 ? 3 : 0);
      int j = jlo + rrow;
      int jcl = min(max(j, 0), SS - 1);
      const float* gsrc = Kb + (size_t)jcl * SH + part * 256 + lane * 4;
      float* dst = ldsf + rrow * (RS4 * 4) + part * 256;
      g2lds16(gsrc, dst);
    }
    if (tid < JC) {
      int j = jlo + tid;
      kwc[tid] = (j >= 0 && j < SS) ? kwb[j] : 0.0f;
    }
    __syncthreads();                   // staging drained

    // union window for both rows: [i-31, i+40]; tab index clamped (the
    // out-of-band tail has decay <= exp(-16) -> ~1e-10 output error)
    int jA = max(max(i - 31, jlo), 0);
    int jB = min(min(i + 40, jlo + JC - 1), SS - 1);
    for (int jb = jA; jb <= jB; jb += 4) {
      int j = jb + g;
      bool val = j <= jB;
      int row = (val ? j : jA) - jlo;  // in [0, JC)
      const float4* kr = kb + row * RS4;
      float da = 0.f, db = 0.f;
      #pragma unroll
      for (int m = 0; m < 12; ++m) {
        float4 kv = kr[u + 16 * m];
        da += dot4(qfa[m], kv);
        db += dot4(qfb[m], kv);
      }
      da += __shfl_xor(da, 1, 64); da += __shfl_xor(da, 2, 64);
      da += __shfl_xor(da, 4, 64); da += __shfl_xor(da, 8, 64);
      db += __shfl_xor(db, 1, 64); db += __shfl_xor(db, 2, 64);
      db += __shfl_xor(db, 4, 64); db += __shfl_xor(db, 8, 64);
      float wfj = val ? kwc[row] : 0.0f;
      float sva = da * wfj, svb = db * wfj;
      int ta = min(max(j - i + 31, 0), 63);
      int tb = min(max(j - i + 23, 0), 63);      // (j - (i+8) + 31)
      float eva = __expf(sva * tab_s[ta]) - 1.0f;
      float evb = __expf(svb * tab_s[tb]) - 1.0f;
      ana += eva * sva; ada += eva;
      anb += evb * svb; adb += evb;
    }
  }

  #pragma unroll
  for (int m = 1; m < 64; m <<= 1) {
    d0a += __shfl_xor(d0a, m, 64);
    d0b += __shfl_xor(d0b, m, 64);
  }
  ana += __shfl_xor(ana, 16, 64); ana += __shfl_xor(ana, 32, 64);
  ada += __shfl_xor(ada, 16, 64); ada += __shfl_xor(ada, 32, 64);
  anb += __shfl_xor(anb, 16, 64); anb += __shfl_xor(anb, 32, 64);
  adb += __shfl_xor(adb, 16, 64); adb += __shfl_xor(adb, 32, 64);
  float nk = Nk[b];
  float sc = (d0a + ana) / (nk + ada) + (d0b + anb) / (nk + adb);
  if (lane == 0) wsum[w] = sc;
  __syncthreads();
  if (tid == 0) {
    float s = 0.f;
    #pragma unroll
    for (int x = 0; x < WV; ++x) s += wsum[x];
    atomicAdd(&acc[b], s);
  }
}

__global__ void finalize_kernel(const float* __restrict__ acc,
                                const float* __restrict__ qsum,
                                float* __restrict__ out) {
  int b = threadIdx.x;
  if (b < SB) out[b] = acc[b] / fmaxf(qsum[b], 1.0f);
}

extern "C" void kernel_launch(void* const* d_in, const int* in_sizes, int n_in,
                              void* d_out, int out_size, void* d_ws, size_t ws_size,
                              hipStream_t stream) {
  const float* Q    = (const float*)d_in[0];
  const float* K    = (const float*)d_in[1];
  const float* qm   = (const float*)d_in[2];
  const float* km   = (const float*)d_in[3];
  const float* temp = (const float*)d_in[4];
  float* ws   = (float*)d_ws;
  float* kw   = ws;
  float* qwv  = ws + SB * SS;
  float* ksum = ws + 2 * SB * SS;
  float* Nk   = ksum + SB * SH;
  float* qsum = Nk + 8;
  float* accb = qsum + 8;
  float* outp = (float*)d_out;

  hipMemsetAsync(ksum, 0, (SB * SH + 24) * sizeof(float), stream);

  norm_kernel<<<2 * SB * SS / 4, 256, 0, stream>>>(Q, K, qm, km, qwv, kw, Nk, qsum);
  ksum_kernel<<<dim3(32, SB), 256, 0, stream>>>(K, kw, ksum);
  band_kernel<<<SB * (SS / TI), 512, 0, stream>>>(Q, K, temp, qwv, kw, ksum, Nk, accb);
  finalize_kernel<<<1, 64, 0, stream>>>(accb, qsum, outp);
}

// Round 5
// 279.640 us; speedup vs baseline: 1.3569x; 1.3569x over previous
//
#include <hip/hip_runtime.h>
#include <math.h>

#define SB 8
#define SS 2048
#define SH 768
#define ALPHA 0.5f
#define WV 16          // waves per block = q-rows per block
#define TI 16
#define JC 16          // k-rows staged per chunk
#define RS4 193        // LDS row stride in float4 (772 floats = 3088 B)
#define NCHUNK 5       // covers [i0-31, i0+48] >= needed [i0-31, i0+47]

// ws float layout:
// 0      : kw   [SB*SS]  = km * (1/||k||)
// 16384  : qw   [SB*SS]  = qm * (1/||q||)
// 32768  : ksum [SB*SH]
// 38912  : Nk[8], qsum[8], acc[8]

__device__ __forceinline__ float dot4(float4 a, float4 b) {
  return a.x*b.x + a.y*b.y + a.z*b.z + a.w*b.w;
}

__device__ __forceinline__ void g2lds16(const float* g, float* l) {
  __builtin_amdgcn_global_load_lds(
      (const __attribute__((address_space(1))) void*)g,
      (__attribute__((address_space(3))) void*)l, 16, 0, 0);
}

// rows 0..SB*SS-1 : K -> kw ; rows SB*SS.. : Q -> qw.  (no atomics here)
__global__ __launch_bounds__(256) void norm_kernel(
    const float* __restrict__ Q, const float* __restrict__ K,
    const float* __restrict__ qm, const float* __restrict__ km,
    float* __restrict__ qw, float* __restrict__ kw) {
  int lane = threadIdx.x & 63;
  int r2 = blockIdx.x * 4 + (threadIdx.x >> 6);
  bool isQ = r2 >= SB * SS;
  int r = isQ ? r2 - SB * SS : r2;
  const float4* rv = (const float4*)((isQ ? Q : K) + (size_t)r * SH);
  float4 a = rv[lane], b4 = rv[lane + 64], c = rv[lane + 128];
  float s = dot4(a, a) + dot4(b4, b4) + dot4(c, c);
  #pragma unroll
  for (int m = 1; m < 64; m <<= 1) s += __shfl_xor(s, m, 64);
  if (lane == 0) {
    float mask = (isQ ? qm : km)[r];
    (isQ ? qw : kw)[r] = mask / fmaxf(sqrtf(s), 1e-12f);
  }
}

// ksum accumulation + folded mask sums (one 2-atomic reduce per block: 512 total)
__global__ __launch_bounds__(256) void ksum_kernel(
    const float* __restrict__ K, const float* __restrict__ kw,
    const float* __restrict__ km, const float* __restrict__ qm,
    float* __restrict__ ksum, float* __restrict__ Nk,
    float* __restrict__ qsum) {
  int b = blockIdx.y, jc = blockIdx.x, t = threadIdx.x;
  __shared__ float wsh[64];
  int j0 = jc * 64;
  if (t < 64) wsh[t] = kw[b * SS + j0 + t];
  __syncthreads();
  float a0 = 0.f, a1 = 0.f, a2 = 0.f;
  const float* base = K + ((size_t)b * SS + j0) * SH;
  for (int jj = 0; jj < 64; jj++) {
    float wv = wsh[jj];
    if (wv != 0.0f) {
      const float* rp = base + (size_t)jj * SH;
      a0 += rp[t] * wv;
      a1 += rp[t + 256] * wv;
      a2 += rp[t + 512] * wv;
    }
  }
  atomicAdd(&ksum[b * SH + t], a0);
  atomicAdd(&ksum[b * SH + t + 256], a1);
  atomicAdd(&ksum[b * SH + t + 512], a2);
  // mask partials for this block's 64 rows (wave 0 only)
  if (t < 64) {
    float pk = km[b * SS + j0 + t];
    float pq = qm[b * SS + j0 + t];
    #pragma unroll
    for (int m = 1; m < 64; m <<= 1) {
      pk += __shfl_xor(pk, m, 64);
      pq += __shfl_xor(pq, m, 64);
    }
    if (t == 0) { atomicAdd(&Nk[b], pk); atomicAdd(&qsum[b], pq); }
  }
}

// One wave per q-row; 16 waves/block share each staged chunk.
__global__ __launch_bounds__(1024, 4) void band_kernel(
    const float* __restrict__ Q, const float* __restrict__ K,
    const float* __restrict__ temp,
    const float* __restrict__ qw, const float* __restrict__ kw,
    const float* __restrict__ ksum, const float* __restrict__ Nk,
    float* __restrict__ acc) {
  __shared__ float4 kb[JC * RS4];     // 49408 B
  __shared__ float tab_s[64];
  __shared__ float kwc[JC];
  __shared__ float wsum[WV];
  int tid = threadIdx.x;
  int w = tid >> 6, lane = tid & 63, g = lane >> 4, u = lane & 15;
  int blk = blockIdx.x;
  int b = blk >> 7;                    // grid = 8 * 128
  int i0 = (blk & 127) * TI;
  int i = i0 + w;
  int r = b * SS + i;
  if (tid < 64) {
    float invt = 1.0f / temp[0];
    tab_s[tid] = __expf(-ALPHA * fabsf((float)(tid - 31))) * invt;
  }
  // load q fragment once, fold in qw (qm/||q||)
  float qwv = qw[r];
  const float4* qr = (const float4*)(Q + (size_t)r * SH);
  float4 qf[12];
  #pragma unroll
  for (int m = 0; m < 12; ++m) {
    float4 v = qr[u + 16 * m];
    v.x *= qwv; v.y *= qwv; v.z *= qwv; v.w *= qwv;
    qf[m] = v;
  }
  // far-field rank-1 term (partial; reduced at the end)
  const float4* ks = (const float4*)(ksum + (size_t)b * SH);
  float d0 = 0.f;
  #pragma unroll
  for (int mm = 0; mm < 3; ++mm) {
    int m = 3 * g + mm;
    d0 += dot4(qf[m], ks[u + 16 * m]);
  }

  float an = 0.f, ad = 0.f;
  const float* Kb = K + (size_t)b * SS * SH;
  const float* kwb = kw + b * SS;
  float* ldsf = (float*)kb;

  for (int c = 0; c < NCHUNK; ++c) {
    int jlo = i0 - 31 + JC * c;
    __syncthreads();                   // LDS reuse guard
    // 16 waves x 3 issues = 48 = 16 rows x 3 parts; wave w stages row w
    #pragma unroll
    for (int part = 0; part < 3; ++part) {
      int j = jlo + w;
      int jcl = min(max(j, 0), SS - 1);
      const float* gsrc = Kb + (size_t)jcl * SH + part * 256 + lane * 4;
      float* dst = ldsf + w * (RS4 * 4) + part * 256;
      g2lds16(gsrc, dst);
    }
    if (tid < JC) {
      int j = jlo + tid;
      kwc[tid] = (j >= 0 && j < SS) ? kwb[j] : 0.0f;
    }
    __syncthreads();                   // staging drained

    int jA = max(max(i - 31, jlo), 0);
    int jB = min(min(i + 32, jlo + JC - 1), SS - 1);
    for (int jb = jA; jb <= jB; jb += 4) {
      int j = jb + g;
      bool val = j <= jB;
      int row = (val ? j : jA) - jlo;  // in [0, JC)
      const float4* kr = kb + row * RS4;
      float d = 0.f;
      #pragma unroll
      for (int m = 0; m < 12; ++m) d += dot4(qf[m], kr[u + 16 * m]);
      d += __shfl_xor(d, 1, 64); d += __shfl_xor(d, 2, 64);
      d += __shfl_xor(d, 4, 64); d += __shfl_xor(d, 8, 64);
      float wfj = val ? kwc[row] : 0.0f;
      float sv = d * wfj;                       // masked sim (incl. qm/norms)
      float lv = sv * tab_s[val ? (j - i + 31) : 0];
      float ev = __expf(lv) - 1.0f;
      an += ev * sv;
      ad += ev;
    }
  }

  #pragma unroll
  for (int m = 1; m < 64; m <<= 1) d0 += __shfl_xor(d0, m, 64);
  an += __shfl_xor(an, 16, 64); an += __shfl_xor(an, 32, 64);
  ad += __shfl_xor(ad, 16, 64); ad += __shfl_xor(ad, 32, 64);
  float sc = (d0 + an) / (Nk[b] + ad);          // qwv==0 -> 0/(Nk) = 0
  if (lane == 0) wsum[w] = sc;
  __syncthreads();
  if (tid == 0) {
    float s = 0.f;
    #pragma unroll
    for (int x = 0; x < WV; ++x) s += wsum[x];
    atomicAdd(&acc[b], s);
  }
}

__global__ void finalize_kernel(const float* __restrict__ acc,
                                const float* __restrict__ qsum,
                                float* __restrict__ out) {
  int b = threadIdx.x;
  if (b < SB) out[b] = acc[b] / fmaxf(qsum[b], 1.0f);
}

extern "C" void kernel_launch(void* const* d_in, const int* in_sizes, int n_in,
                              void* d_out, int out_size, void* d_ws, size_t ws_size,
                              hipStream_t stream) {
  const float* Q    = (const float*)d_in[0];
  const float* K    = (const float*)d_in[1];
  const float* qm   = (const float*)d_in[2];
  const float* km   = (const float*)d_in[3];
  const float* temp = (const float*)d_in[4];
  float* ws   = (float*)d_ws;
  float* kw   = ws;
  float* qwv  = ws + SB * SS;
  float* ksum = ws + 2 * SB * SS;
  float* Nk   = ksum + SB * SH;
  float* qsum = Nk + 8;
  float* accb = qsum + 8;
  float* outp = (float*)d_out;

  hipMemsetAsync(ksum, 0, (SB * SH + 24) * sizeof(float), stream);

  norm_kernel<<<2 * SB * SS / 4, 256, 0, stream>>>(Q, K, qm, km, qwv, kw);
  ksum_kernel<<<dim3(32, SB), 256, 0, stream>>>(K, kw, km, qm, ksum, Nk, qsum);
  band_kernel<<<SB * (SS / TI), 1024, 0, stream>>>(Q, K, temp, qwv, kw, ksum, Nk, accb);
  finalize_kernel<<<1, 64, 0, stream>>>(accb, qsum, outp);
}

// Round 7
// 195.098 us; speedup vs baseline: 1.9449x; 1.4333x over previous
//
#include <hip/hip_runtime.h>
#include <math.h>

#define SB 8
#define SS 2048
#define SH 768
#define ALPHA 0.5f
#define TI 8           // q-rows per block (8 waves x 1)
#define JC 16          // k-rows staged per chunk
#define NCHUNK 5       // stages [i0-31, i0+48] >= band union [i0-31, i0+39]
#define RSH 776        // LDS row stride in halves (1552 B, 16B-aligned)

// ws float layout:
// 0      : kw   [SB*SS]  = km * (1/||k||)
// 16384  : ksum [SB*SH]
// 22528  : Nk[8], qsum[8], acc[8]

typedef __fp16 half2_t __attribute__((ext_vector_type(2)));

__device__ __forceinline__ float dot4(float4 a, float4 b) {
  return a.x*b.x + a.y*b.y + a.z*b.z + a.w*b.w;
}

__device__ __forceinline__ float h2dot(half2_t a, half2_t b, float c) {
#if __has_builtin(__builtin_amdgcn_fdot2)
  return __builtin_amdgcn_fdot2(a, b, c, false);
#else
  return fmaf((float)a.x, (float)b.x, fmaf((float)a.y, (float)b.y, c));
#endif
}

__device__ __forceinline__ half2_t b2h2(unsigned int u) {
  return __builtin_bit_cast(half2_t, u);
}

// Fused K pass: per-row norm -> kw, masked-normalized ksum, Nk, qsum.
// grid (32, SB), block 256 = 4 waves x 16 rows.
__global__ __launch_bounds__(256) void kprep_kernel(
    const float* __restrict__ K, const float* __restrict__ km,
    const float* __restrict__ qm,
    float* __restrict__ kw, float* __restrict__ ksum,
    float* __restrict__ Nk, float* __restrict__ qsum) {
  __shared__ float4 red[4][3][64];     // 12 KB
  int b = blockIdx.y, jc = blockIdx.x, t = threadIdx.x;
  int w = t >> 6, lane = t & 63;
  int j0 = jc * 64;
  float4 acc0 = {0,0,0,0}, acc1 = {0,0,0,0}, acc2 = {0,0,0,0};
  for (int jj = 0; jj < 16; ++jj) {
    int j = j0 + 16 * w + jj;
    const float4* rp = (const float4*)(K + ((size_t)b * SS + j) * SH);
    float4 a = rp[lane], b4 = rp[lane + 64], c4 = rp[lane + 128];
    float ss = dot4(a, a) + dot4(b4, b4) + dot4(c4, c4);
    #pragma unroll
    for (int m = 1; m < 64; m <<= 1) ss += __shfl_xor(ss, m, 64);
    float kwj = km[b * SS + j] / fmaxf(sqrtf(ss), 1e-12f);
    if (lane == 0) kw[b * SS + j] = kwj;
    acc0.x += a.x*kwj;  acc0.y += a.y*kwj;  acc0.z += a.z*kwj;  acc0.w += a.w*kwj;
    acc1.x += b4.x*kwj; acc1.y += b4.y*kwj; acc1.z += b4.z*kwj; acc1.w += b4.w*kwj;
    acc2.x += c4.x*kwj; acc2.y += c4.y*kwj; acc2.z += c4.z*kwj; acc2.w += c4.w*kwj;
  }
  red[w][0][lane] = acc0; red[w][1][lane] = acc1; red[w][2][lane] = acc2;
  __syncthreads();
  if (t < 192) {
    int s = t >> 6, l = t & 63;
    float4 r0 = red[0][s][l], r1 = red[1][s][l], r2 = red[2][s][l], r3 = red[3][s][l];
    float4 tot = {r0.x+r1.x+r2.x+r3.x, r0.y+r1.y+r2.y+r3.y,
                  r0.z+r1.z+r2.z+r3.z, r0.w+r1.w+r2.w+r3.w};
    float* kp = ksum + b * SH + (s * 64 + l) * 4;
    atomicAdd(kp + 0, tot.x); atomicAdd(kp + 1, tot.y);
    atomicAdd(kp + 2, tot.z); atomicAdd(kp + 3, tot.w);
  }
  // mask partials for this block's 64 rows (wave 0)
  if (t < 64) {
    float pk = km[b * SS + j0 + t];
    float pq = qm[b * SS + j0 + t];
    #pragma unroll
    for (int m = 1; m < 64; m <<= 1) {
      pk += __shfl_xor(pk, m, 64);
      pq += __shfl_xor(pq, m, 64);
    }
    if (t == 0) { atomicAdd(&Nk[b], pk); atomicAdd(&qsum[b], pq); }
  }
}

// Band kernel: 8 waves x 1 q-row; raw-f16 K staged in LDS with register
// prefetch; q-norm computed inline; XCD-swizzled block->(b,i0) mapping.
__global__ __launch_bounds__(512, 4) void band_kernel(
    const float* __restrict__ Q, const float* __restrict__ K,
    const float* __restrict__ temp, const float* __restrict__ qm,
    const float* __restrict__ kw,
    const float* __restrict__ ksum, const float* __restrict__ Nk,
    float* __restrict__ acc) {
  __shared__ __fp16 kh[JC * RSH];      // 24832 B
  __shared__ float tab_s[64];
  __shared__ float kwc[JC];
  __shared__ float wsum[8];
  int tid = threadIdx.x;
  int w = tid >> 6, lane = tid & 63, g = lane >> 4, u = lane & 15;
  // XCD swizzle: consecutive work per XCD -> per-XCD L2 holds one batch's K
  int blk = blockIdx.x;
  int work = (blk & 7) * 256 + (blk >> 3);   // grid = 2048
  int b = work >> 8;
  int i0 = (work & 255) * TI;
  int i = i0 + w;
  int r = b * SS + i;
  if (tid < 64) {
    float invt = 1.0f / temp[0];
    tab_s[tid] = __expf(-ALPHA * fabsf((float)(tid - 31))) * invt;
  }
  // ---- prologue: load q (layout matches k-LDS b128 tiling), norm, d0, cvt f16
  const float4* qr = (const float4*)(Q + (size_t)r * SH);
  const float4* ks = (const float4*)(ksum + (size_t)b * SH);
  half2_t qh[24];
  float ss = 0.f, d0 = 0.f;
  {
    float4 qa[6], qb[6];
    #pragma unroll
    for (int m = 0; m < 6; ++m) {
      qa[m] = qr[2 * (u + 16 * m)];
      qb[m] = qr[2 * (u + 16 * m) + 1];
      ss += dot4(qa[m], qa[m]) + dot4(qb[m], qb[m]);
    }
    #pragma unroll
    for (int m = 0; m < 6; ++m) {
      d0 += dot4(qa[m], ks[2 * (u + 16 * m)]);
      d0 += dot4(qb[m], ks[2 * (u + 16 * m) + 1]);
      qh[4 * m + 0] = __builtin_amdgcn_cvt_pkrtz(qa[m].x, qa[m].y);
      qh[4 * m + 1] = __builtin_amdgcn_cvt_pkrtz(qa[m].z, qa[m].w);
      qh[4 * m + 2] = __builtin_amdgcn_cvt_pkrtz(qb[m].x, qb[m].y);
      qh[4 * m + 3] = __builtin_amdgcn_cvt_pkrtz(qb[m].z, qb[m].w);
    }
  }
  #pragma unroll
  for (int m = 1; m < 16; m <<= 1) {    // reduce over u-group only
    ss += __shfl_xor(ss, m, 64);
    d0 += __shfl_xor(d0, m, 64);
  }
  float qw = qm[r] / fmaxf(sqrtf(ss), 1e-12f);
  d0 *= qw;                              // all lanes hold full d0 now

  const float* Kb = K + (size_t)b * SS * SH;
  const float* kwb = kw + b * SS;
  int rr = tid >> 5, cl = tid & 31;      // staging role: row rr (0..15), col cl

  // prefetch chunk 0
  float4 pf[6];
  {
    int j = i0 - 31 + rr;
    int jcl = min(max(j, 0), SS - 1);
    const float4* src = (const float4*)(Kb + (size_t)jcl * SH);
    #pragma unroll
    for (int s = 0; s < 6; ++s) pf[s] = src[cl + 32 * s];
  }

  float an = 0.f, ad = 0.f;
  for (int c = 0; c < NCHUNK; ++c) {
    int jlo = i0 - 31 + JC * c;
    __syncthreads();                     // prev compute done; pf drained
    // write staged rows as raw f16
    {
      unsigned long long* dst =
          (unsigned long long*)(kh + rr * RSH) + cl;   // 8B units
      #pragma unroll
      for (int s = 0; s < 6; ++s) {
        half2_t lo = __builtin_amdgcn_cvt_pkrtz(pf[s].x, pf[s].y);
        half2_t hi = __builtin_amdgcn_cvt_pkrtz(pf[s].z, pf[s].w);
        unsigned long long v =
            (unsigned long long)__builtin_bit_cast(unsigned int, lo) |
            ((unsigned long long)__builtin_bit_cast(unsigned int, hi) << 32);
        dst[32 * s] = v;
      }
      if (tid < JC) {
        int j = jlo + tid;
        kwc[tid] = (j >= 0 && j < SS) ? kwb[j] : 0.0f;
      }
    }
    __syncthreads();                     // staged data visible
    // issue prefetch for c+1 AFTER the barrier (stays in flight over compute)
    if (c + 1 < NCHUNK) {
      int j = jlo + JC + rr;
      int jcl = min(max(j, 0), SS - 1);
      const float4* src = (const float4*)(Kb + (size_t)jcl * SH);
      #pragma unroll
      for (int s = 0; s < 6; ++s) pf[s] = src[cl + 32 * s];
    }
    // compute: this wave's j-window within the staged chunk
    int jA = max(max(i - 31, jlo), 0);
    int jB = min(min(i + 32, jlo + JC - 1), SS - 1);
    for (int jb = jA; jb <= jB; jb += 4) {
      int j = jb + g;
      bool val = j <= jB;
      int row = (val ? j : jA) - jlo;    // in [0, JC)
      const uint4* kr = (const uint4*)(kh + row * RSH);
      float d = 0.f;
      #pragma unroll
      for (int m = 0; m < 6; ++m) {
        uint4 kv = kr[u + 16 * m];
        d = h2dot(qh[4*m+0], b2h2(kv.x), d);
        d = h2dot(qh[4*m+1], b2h2(kv.y), d);
        d = h2dot(qh[4*m+2], b2h2(kv.z), d);
        d = h2dot(qh[4*m+3], b2h2(kv.w), d);
      }
      d += __shfl_xor(d, 1, 64); d += __shfl_xor(d, 2, 64);
      d += __shfl_xor(d, 4, 64); d += __shfl_xor(d, 8, 64);
      float wfj = val ? (kwc[row] * qw) : 0.0f;
      float sv = d * wfj;                // masked sim (incl. qm & both norms)
      float lv = sv * tab_s[val ? (j - i + 31) : 0];
      float ev = __expf(lv) - 1.0f;
      an += ev * sv;
      ad += ev;
    }
  }

  an += __shfl_xor(an, 16, 64); an += __shfl_xor(an, 32, 64);
  ad += __shfl_xor(ad, 16, 64); ad += __shfl_xor(ad, 32, 64);
  float sc = (d0 + an) / (Nk[b] + ad);   // qm==0 -> numerator 0 -> 0
  if (lane == 0) wsum[w] = sc;
  __syncthreads();
  if (tid == 0) {
    float s = 0.f;
    #pragma unroll
    for (int x = 0; x < 8; ++x) s += wsum[x];
    atomicAdd(&acc[b], s);
  }
}

__global__ void finalize_kernel(const float* __restrict__ acc,
                                const float* __restrict__ qsum,
                                float* __restrict__ out) {
  int b = threadIdx.x;
  if (b < SB) out[b] = acc[b] / fmaxf(qsum[b], 1.0f);
}

extern "C" void kernel_launch(void* const* d_in, const int* in_sizes, int n_in,
                              void* d_out, int out_size, void* d_ws, size_t ws_size,
                              hipStream_t stream) {
  const float* Q    = (const float*)d_in[0];
  const float* K    = (const float*)d_in[1];
  const float* qm   = (const float*)d_in[2];
  const float* km   = (const float*)d_in[3];
  const float* temp = (const float*)d_in[4];
  float* ws   = (float*)d_ws;
  float* kw   = ws;
  float* ksum = ws + SB * SS;
  float* Nk   = ksum + SB * SH;
  float* qsum = Nk + 8;
  float* accb = qsum + 8;
  float* outp = (float*)d_out;

  (void)hipMemsetAsync(ksum, 0, (SB * SH + 24) * sizeof(float), stream);

  kprep_kernel<<<dim3(32, SB), 256, 0, stream>>>(K, km, qm, kw, ksum, Nk, qsum);
  band_kernel<<<SB * (SS / TI), 512, 0, stream>>>(Q, K, temp, qm, kw, ksum, Nk, accb);
  finalize_kernel<<<1, 64, 0, stream>>>(accb, qsum, outp);
}

// Round 8
// 189.722 us; speedup vs baseline: 2.0000x; 1.0283x over previous
//
#include <hip/hip_runtime.h>
#include <math.h>

#define SB 8
#define SS 2048
#define SH 768
#define ALPHA 0.5f
#define TI 16          // q-rows per block
#define NCH 5          // chunks of 16 j-rows: jlo = i0-32+16c, covers [i0-32, i0+47]
#define RSH 776        // LDS k-row stride in halves (1552 B)

// ws float layout:
// 0      : kw   [SB*SS]
// 16384  : ksum [SB*SH]
// 22528  : Nk[8], qsum[8], acc[8], cnt[8]

typedef __fp16 f16x8 __attribute__((ext_vector_type(8)));
typedef float f32x4 __attribute__((ext_vector_type(4)));

__device__ __forceinline__ float dot4(float4 a, float4 b) {
  return a.x*b.x + a.y*b.y + a.z*b.z + a.w*b.w;
}
__device__ __forceinline__ unsigned int pk2(float a, float b) {
  return __builtin_bit_cast(unsigned int, __builtin_amdgcn_cvt_pkrtz(a, b));
}

// K prep: per-row norm -> kw, masked-normalized ksum, Nk, qsum.
// grid (64, SB), block 256 = 4 waves x 8 rows.
__global__ __launch_bounds__(256) void kprep_kernel(
    const float* __restrict__ K, const float* __restrict__ km,
    const float* __restrict__ qm,
    float* __restrict__ kw, float* __restrict__ ksum,
    float* __restrict__ Nk, float* __restrict__ qsum) {
  __shared__ float4 red[4][3][64];     // 12 KB
  int b = blockIdx.y, jc = blockIdx.x, t = threadIdx.x;
  int w = t >> 6, lane = t & 63;
  int j0 = jc * 32;
  float4 acc0 = {0,0,0,0}, acc1 = {0,0,0,0}, acc2 = {0,0,0,0};
  for (int jj = 0; jj < 8; ++jj) {
    int j = j0 + 8 * w + jj;
    const float4* rp = (const float4*)(K + ((size_t)b * SS + j) * SH);
    float4 a = rp[lane], b4 = rp[lane + 64], c4 = rp[lane + 128];
    float ss = dot4(a, a) + dot4(b4, b4) + dot4(c4, c4);
    #pragma unroll
    for (int m = 1; m < 64; m <<= 1) ss += __shfl_xor(ss, m, 64);
    float kwj = km[b * SS + j] / fmaxf(sqrtf(ss), 1e-12f);
    if (lane == 0) kw[b * SS + j] = kwj;
    acc0.x += a.x*kwj;  acc0.y += a.y*kwj;  acc0.z += a.z*kwj;  acc0.w += a.w*kwj;
    acc1.x += b4.x*kwj; acc1.y += b4.y*kwj; acc1.z += b4.z*kwj; acc1.w += b4.w*kwj;
    acc2.x += c4.x*kwj; acc2.y += c4.y*kwj; acc2.z += c4.z*kwj; acc2.w += c4.w*kwj;
  }
  red[w][0][lane] = acc0; red[w][1][lane] = acc1; red[w][2][lane] = acc2;
  __syncthreads();
  if (t < 192) {
    int s = t >> 6, l = t & 63;
    float4 r0 = red[0][s][l], r1 = red[1][s][l], r2 = red[2][s][l], r3 = red[3][s][l];
    float* kp = ksum + b * SH + (s * 64 + l) * 4;
    atomicAdd(kp + 0, r0.x+r1.x+r2.x+r3.x);
    atomicAdd(kp + 1, r0.y+r1.y+r2.y+r3.y);
    atomicAdd(kp + 2, r0.z+r1.z+r2.z+r3.z);
    atomicAdd(kp + 3, r0.w+r1.w+r2.w+r3.w);
  }
  if (t < 32) {
    float pkm = km[b * SS + j0 + t];
    float pqm = qm[b * SS + j0 + t];
    #pragma unroll
    for (int m = 1; m < 32; m <<= 1) {
      pkm += __shfl_xor(pkm, m, 64);
      pqm += __shfl_xor(pqm, m, 64);
    }
    if (t == 0) { atomicAdd(&Nk[b], pkm); atomicAdd(&qsum[b], pqm); }
  }
}

// MFMA band kernel: 16 q-rows per block, 4 waves split K=768 into 192-slices.
// S-tile 16x16 per chunk via mfma_f32_16x16x32_f16; partials summed in LDS
// before softmax-term epilogue (wave 0). Finalize folded via per-batch counter.
__global__ __launch_bounds__(256, 4) void band_kernel(
    const float* __restrict__ Q, const float* __restrict__ K,
    const float* __restrict__ temp, const float* __restrict__ qm,
    const float* __restrict__ kw,
    const float* __restrict__ ksum, const float* __restrict__ Nkp,
    const float* __restrict__ qsum,
    float* __restrict__ acc, int* __restrict__ cnt, float* __restrict__ out) {
  __shared__ __fp16 kh[TI * RSH];          // 24832 B
  __shared__ float sC[1024];               // 4 KB: C partials / prologue scratch
  __shared__ float tab_s[64];
  __shared__ float qws[TI], d0s[TI], kwc[TI];
  int tid = threadIdx.x;
  int w = tid >> 6, lane = tid & 63;
  int l15 = lane & 15, quad = lane >> 4;
  int blk = blockIdx.x;
  int work = (blk & 7) * 128 + (blk >> 3);   // XCD swizzle (grid 1024)
  int b = work >> 7;
  int i0 = (work & 127) * TI;
  if (tid < 64) {
    float invt = 1.0f / temp[0];
    tab_s[tid] = __expf(-ALPHA * fabsf((float)(tid - 31))) * invt;
  }
  // ---- prologue: A fragments (f16), f32 norm/d0 partials
  f16x8 afr[6];
  {
    const float* qrow = Q + (size_t)(b * SS + i0 + l15) * SH + w * 192 + quad * 8;
    const float* ksb  = ksum + (size_t)b * SH + w * 192 + quad * 8;
    float ssp = 0.f, d0p = 0.f;
    #pragma unroll
    for (int s = 0; s < 6; ++s) {
      float4 x0 = *(const float4*)(qrow + 32 * s);
      float4 x1 = *(const float4*)(qrow + 32 * s + 4);
      float4 k0 = *(const float4*)(ksb + 32 * s);
      float4 k1 = *(const float4*)(ksb + 32 * s + 4);
      ssp += dot4(x0, x0) + dot4(x1, x1);
      d0p += dot4(x0, k0) + dot4(x1, k1);
      uint4 u = make_uint4(pk2(x0.x,x0.y), pk2(x0.z,x0.w),
                           pk2(x1.x,x1.y), pk2(x1.z,x1.w));
      afr[s] = __builtin_bit_cast(f16x8, u);
    }
    sC[(w * 64 + lane) * 2]     = ssp;
    sC[(w * 64 + lane) * 2 + 1] = d0p;
  }
  __syncthreads();
  if (tid < TI) {
    float ss = 0.f, dd = 0.f;
    #pragma unroll
    for (int p = 0; p < 16; ++p) {
      int idx = ((p >> 2) * 64 + (p & 3) * 16 + tid) * 2;
      ss += sC[idx]; dd += sC[idx + 1];
    }
    qws[tid] = qm[b * SS + i0 + tid] / fmaxf(sqrtf(ss), 1e-12f);
    d0s[tid] = dd;
  }
  float nk = Nkp[b];
  const float* Kb = K + (size_t)b * SS * SH;
  const float* kwb = kw + b * SS;

  // staging role: row prow (0..15), segment pseg (48 floats)
  int prow = tid >> 4, pseg = tid & 15;
  float4 pf[12];
  {
    int jcl = min(max(i0 - 32 + prow, 0), SS - 1);
    const float4* src = (const float4*)(Kb + (size_t)jcl * SH + pseg * 48);
    #pragma unroll
    for (int u = 0; u < 12; ++u) pf[u] = src[u];
  }

  float anv[4] = {0,0,0,0}, adv[4] = {0,0,0,0};
  for (int c = 0; c < NCH; ++c) {
    int jlo = i0 - 32 + 16 * c;
    __syncthreads();                       // #1: prev MFMA B-reads + epilogue done
    {
      uint4* dst = (uint4*)(kh + prow * RSH + pseg * 48);
      #pragma unroll
      for (int u = 0; u < 6; ++u) {
        float4 a = pf[2*u], bb = pf[2*u+1];
        dst[u] = make_uint4(pk2(a.x,a.y), pk2(a.z,a.w), pk2(bb.x,bb.y), pk2(bb.z,bb.w));
      }
      if (tid < TI) {
        int j = jlo + tid;
        kwc[tid] = (j >= 0 && j < SS) ? kwb[j] : 0.0f;
      }
    }
    __syncthreads();                       // #2: B visible
    if (c + 1 < NCH) {                     // prefetch AFTER barrier (stays in flight)
      int jcl = min(max(jlo + 16 + prow, 0), SS - 1);
      const float4* src = (const float4*)(Kb + (size_t)jcl * SH + pseg * 48);
      #pragma unroll
      for (int u = 0; u < 12; ++u) pf[u] = src[u];
    }
    // MFMA: this wave's K-slice
    f32x4 d = {0.f, 0.f, 0.f, 0.f};
    {
      const __fp16* bbase = kh + l15 * RSH + w * 192 + quad * 8;
      #pragma unroll
      for (int s = 0; s < 6; ++s) {
        f16x8 bf = *(const f16x8*)(bbase + 32 * s);
        d = __builtin_amdgcn_mfma_f32_16x16x32_f16(afr[s], bf, d, 0, 0, 0);
      }
    }
    {
      float4* cw = (float4*)sC;
      cw[w * 64 + lane] = make_float4(d[0], d[1], d[2], d[3]);
    }
    __syncthreads();                       // #3: C partials visible
    if (w == 0) {                          // epilogue (wave-uniform branch)
      const float4* cr = (const float4*)sC;
      float4 t0 = cr[lane], t1 = cr[64 + lane], t2 = cr[128 + lane], t3 = cr[192 + lane];
      float sx[4] = {t0.x+t1.x+t2.x+t3.x, t0.y+t1.y+t2.y+t3.y,
                     t0.z+t1.z+t2.z+t3.z, t0.w+t1.w+t2.w+t3.w};
      int base = jlo - i0 + 31 + l15;      // l15 = column (k-row within chunk)
      float kwv = kwc[l15];
      #pragma unroll
      for (int reg = 0; reg < 4; ++reg) {
        int rowl = quad * 4 + reg;
        float sv = sx[reg] * qws[rowl] * kwv;
        int idx = min(max(base - rowl, 0), 63);
        float ev = __expf(sv * tab_s[idx]) - 1.0f;
        anv[reg] += ev * sv;
        adv[reg] += ev;
      }
    }
  }

  if (w == 0) {
    float tot = 0.f;
    #pragma unroll
    for (int reg = 0; reg < 4; ++reg) {
      float an = anv[reg], ad = adv[reg];
      an += __shfl_xor(an, 1, 64); an += __shfl_xor(an, 2, 64);
      an += __shfl_xor(an, 4, 64); an += __shfl_xor(an, 8, 64);
      ad += __shfl_xor(ad, 1, 64); ad += __shfl_xor(ad, 2, 64);
      ad += __shfl_xor(ad, 4, 64); ad += __shfl_xor(ad, 8, 64);
      int rowl = quad * 4 + reg;
      tot += (qws[rowl] * d0s[rowl] + an) / (nk + ad);
    }
    tot += __shfl_xor(tot, 16, 64);        // sum across quads only
    tot += __shfl_xor(tot, 32, 64);
    if (lane == 0) {
      atomicAdd(&acc[b], tot);
      __threadfence();
      if (atomicAdd(&cnt[b], 1) == 127) {  // last of 128 blocks for batch b
        float a = atomicAdd(&acc[b], 0.0f);
        out[b] = a / fmaxf(qsum[b], 1.0f);
      }
    }
  }
}

extern "C" void kernel_launch(void* const* d_in, const int* in_sizes, int n_in,
                              void* d_out, int out_size, void* d_ws, size_t ws_size,
                              hipStream_t stream) {
  const float* Q    = (const float*)d_in[0];
  const float* K    = (const float*)d_in[1];
  const float* qm   = (const float*)d_in[2];
  const float* km   = (const float*)d_in[3];
  const float* temp = (const float*)d_in[4];
  float* ws   = (float*)d_ws;
  float* kw   = ws;
  float* ksum = ws + SB * SS;
  float* Nk   = ksum + SB * SH;
  float* qsum = Nk + 8;
  float* accb = qsum + 8;
  int*   cnt  = (int*)(accb + 8);
  float* outp = (float*)d_out;

  (void)hipMemsetAsync(ksum, 0, (SB * SH + 32) * sizeof(float), stream);

  kprep_kernel<<<dim3(64, SB), 256, 0, stream>>>(K, km, qm, kw, ksum, Nk, qsum);
  band_kernel<<<SB * (SS / TI), 256, 0, stream>>>(Q, K, temp, qm, kw, ksum, Nk,
                                                  qsum, accb, cnt, outp);
}